// Round 16
// baseline (24.463 us; speedup 1.0000x reference)
//
#include <hip/hip_runtime.h>

#define NCLS 19
#define BINS 51
#define NPIX 4096
#define NFEAT 256
#define VCAP 256                   // staged values per wave (chunked beyond)
#define FPB 8                      // features per block (= waves per block)
#define NBX (NFEAT / FPB)          // 32 blocks in x
#define NPART (NBX * (NCLS - 1))   // 576 per-block partials
#define TWO_PI_F 6.2831853071795864769f
#define LOG2E_F 1.4426950408889634f
#define EXP2F(v) __builtin_amdgcn_exp2f(v)

#define ST_AGENT(p, v) __hip_atomic_store((p), (v), __ATOMIC_RELAXED, __HIP_MEMORY_SCOPE_AGENT)
#define LD_AGENT(p)    __hip_atomic_load((p), __ATOMIC_RELAXED, __HIP_MEMORY_SCOPE_AGENT)

__device__ __forceinline__ unsigned mbcnt64(unsigned long long m) {
    unsigned r = __builtin_amdgcn_mbcnt_lo((unsigned)m, 0u);
    return __builtin_amdgcn_mbcnt_hi((unsigned)(m >> 32), r);
}

// ws layout: float partial[576] @ 0 (2304 B); int ncls[32] @ 2304
// No memset node: every partial cell + ncls entry is overwritten every launch.
__global__ __launch_bounds__(512)
void hist_main(const float* __restrict__ x, const int* __restrict__ lab,
               float* __restrict__ partial, int* __restrict__ ncls) {
    const int cm1  = blockIdx.y;                  // 0..17
    const int c    = cm1 + 1;
    const int tid  = threadIdx.x;
    const int lane = tid & 63;
    const int wv   = tid >> 6;                    // 0..7
    const int f    = blockIdx.x * FPB + wv;       // this wave's feature

    __shared__ unsigned short idx_lds[FPB][512];  // class-c pixel indices (u16), 8 KB
    __shared__ __align__(16) float val[FPB][VCAP + 8];
    __shared__ int   n_sh[FPB];
    __shared__ float s_loss[FPB];

    // ---- Phase 1: wave wv ballot-compacts its 512-pixel slice ----
    const int4* labv = (const int4*)lab;
    unsigned short* myidx = idx_lds[wv];
    unsigned cnt = 0;

#define SUBSCAN(L, S)                                                 \
    {                                                                 \
        bool in = ((L) == c);                                         \
        unsigned long long m = __ballot(in);                          \
        if (in) myidx[cnt + mbcnt64(m)] = (unsigned short)(pbase + (S)); \
        cnt += (unsigned)__popcll(m);                                 \
    }

    #pragma unroll
    for (int it = 0; it < 2; ++it) {              // 2 × 64 int4 = 512 px
        int b4    = wv * 128 + it * 64 + lane;
        int4 lv   = labv[b4];
        int pbase = b4 * 4;
        SUBSCAN(lv.x, 0)
        SUBSCAN(lv.y, 1)
        SUBSCAN(lv.z, 2)
        SUBSCAN(lv.w, 3)
    }
#undef SUBSCAN

    if (lane == 0) n_sh[wv] = (int)cnt;
    __syncthreads();                              // barrier 1

    int n = 0;
    #pragma unroll
    for (int s = 0; s < FPB; ++s) n += n_sh[s];   // block-uniform
    if (blockIdx.x == 0 && tid == 0) ST_AGENT(&ncls[c], n);

    if (n == 0) {                                 // still must overwrite our cell
        if (tid == 0) ST_AGENT(&partial[cm1 * NBX + blockIdx.x], 0.f);
        return;                                   // block-uniform: safe
    }

    // ---- Phase 2 (per wave): gather own feature row over 8 segments + stats ----
    const float* xrow  = x + (size_t)f * NPIX;
    float*       myval = val[wv];
    float s1 = 0.f, s2 = 0.f;
    {
        int pos = 0;
        #pragma unroll
        for (int s = 0; s < FPB; ++s) {
            int ns_ = n_sh[s];
            const unsigned short* seg = idx_lds[s];
            for (int i = lane; i < ns_; i += 64) {
                float v = xrow[seg[i]];           // scattered, L1/L2-resident
                int j = pos + i;
                if (j < VCAP) myval[j] = v;
                s1 += v;
                s2 = fmaf(v, v, s2);
            }
            pos += ns_;
        }
    }
    #pragma unroll
    for (int off = 32; off; off >>= 1) {
        s1 += __shfl_xor(s1, off, 64);
        s2 += __shfl_xor(s2, off, 64);
    }
    const float fn  = (float)n;
    const float miu = s1 / fn;
    const float var = fmaxf(s2 / fn - miu * miu, 1e-12f);

    // ---- Phase 3 (per wave): KDE, lane = bin, poly-fma, 4 exp2 chains ----
    const float binv = -5.0f + 0.2f * (float)lane;
    const float cu   = (-12.5f / var) * LOG2E_F;  // -0.5/(var*0.04)*log2e
    const float bl   = -2.f * cu * binv;
    const float al   = cu * binv * binv;          // arg = (cu*v+bl)*v+al
    float a0 = 0.f, a1 = 0.f, a2 = 0.f, a3 = 0.f;

    for (int t0 = 0; t0 < n; t0 += VCAP) {
        if (t0 > 0) {                             // rare re-gather chunk (n > VCAP)
            int pos = 0;
            #pragma unroll
            for (int s = 0; s < FPB; ++s) {
                int ns_ = n_sh[s];
                const unsigned short* seg = idx_lds[s];
                for (int i = lane; i < ns_; i += 64) {
                    int j = pos + i - t0;
                    if (j >= 0 && j < VCAP) myval[j] = xrow[seg[i]];
                }
                pos += ns_;
            }
        }
        int ns  = n - t0; if (ns > VCAP) ns = VCAP;
        int ns4 = (ns + 3) & ~3;
        if (lane < ns4 - ns) myval[ns + lane] = 1e19f;   // sentinel: exp2 -> 0
        #pragma unroll 2
        for (int i = 0; i < ns4; i += 4) {
            float4 v = *(const float4*)&myval[i];        // same-addr broadcast read
            a0 += EXP2F(fmaf(fmaf(cu, v.x, bl), v.x, al));
            a1 += EXP2F(fmaf(fmaf(cu, v.y, bl), v.y, al));
            a2 += EXP2F(fmaf(fmaf(cu, v.z, bl), v.z, al));
            a3 += EXP2F(fmaf(fmaf(cu, v.w, bl), v.w, al));
        }
    }

    // ---- Phase 4 (per wave): normalize + smooth-L1 ----
    float kde = (a0 + a1) + (a2 + a3);
    float vs  = var * 0.04f;
    float dt  = binv - miu;
    float tg  = EXP2F(((-0.5f / var) * LOG2E_F) * (dt * dt));
    if (lane >= BINS) { kde = 0.f; tg = 0.f; }
    float sv = kde * rsqrtf(TWO_PI_F * vs);
    float tt = tg  * rsqrtf(TWO_PI_F * var);
    float ssum = sv, tsum = tt;
    #pragma unroll
    for (int off = 32; off; off >>= 1) {
        ssum += __shfl_xor(ssum, off, 64);
        tsum += __shfl_xor(tsum, off, 64);
    }
    float hist  = sv / fmaxf(ssum, 1e-12f);
    float tnorm = tt / tsum;
    float diff  = hist - tnorm;
    float ad    = fabsf(diff);
    float sl1   = (ad < 1.0f) ? 0.5f * diff * diff : (ad - 0.5f);
    if (lane >= BINS) sl1 = 0.f;
    #pragma unroll
    for (int off = 32; off; off >>= 1) sl1 += __shfl_xor(sl1, off, 64);
    if (lane == 0) s_loss[wv] = sl1;
    __syncthreads();                              // barrier 2 (block-uniform path)

    if (tid == 0) {
        float t = 0.f;
        #pragma unroll
        for (int s = 0; s < FPB; ++s) t += s_loss[s];
        ST_AGENT(&partial[cm1 * NBX + blockIdx.x], t);
    }
}

// ---- finale: deterministic f64 reduction of 576 cells (agent loads) ----
__global__ __launch_bounds__(256)
void hist_final(const float* __restrict__ partial, const int* __restrict__ ncls,
                float* __restrict__ out) {
    const int tid = threadIdx.x, lane = tid & 63, wave = tid >> 6;
    __shared__ double sd[4];

    double s = 0.0;
    for (int i = tid; i < NPART; i += 256)
        s += (double)LD_AGENT(&partial[i]);
    #pragma unroll
    for (int off = 32; off; off >>= 1) s += __shfl_xor(s, off, 64);
    if (lane == 0) sd[wave] = s;
    __syncthreads();
    if (tid == 0) {
        double tot = sd[0] + sd[1] + sd[2] + sd[3];
        int active = 0;
        for (int cc = 1; cc < NCLS; ++cc) active += (LD_AGENT(&ncls[cc]) > 0) ? 1 : 0;
        double loss = tot / (double)(NFEAT * BINS) / ((double)active + 1e-12);
        out[0] = (float)loss;
    }
}

extern "C" void kernel_launch(void* const* d_in, const int* in_sizes, int n_in,
                              void* d_out, int out_size, void* d_ws, size_t ws_size,
                              hipStream_t stream) {
    const float* x   = (const float*)d_in[0];
    const int*   lab = (const int*)d_in[1];
    float* out       = (float*)d_out;
    float* partial   = (float*)d_ws;
    int*   ncls      = (int*)((char*)d_ws + 2304);

    hipLaunchKernelGGL(hist_main, dim3(NBX, NCLS - 1), dim3(512), 0, stream,
                       x, lab, partial, ncls);
    hipLaunchKernelGGL(hist_final, dim3(1), dim3(256), 0, stream,
                       partial, ncls, out);
}

// Round 17
// 23.375 us; speedup vs baseline: 1.0466x; 1.0466x over previous
//
#include <hip/hip_runtime.h>

#define NCLS 19
#define BINS 51
#define NPIX 4096
#define NFEAT 256
#define VCAP 320                   // staged values per wave (chunked beyond)
#define FPB 4                      // features per block (= waves per block)
#define NBX (NFEAT / FPB)          // 64 blocks in x
#define TWO_PI_F 6.2831853071795864769f
#define LOG2E_F 1.4426950408889634f
#define EXP2F(v) __builtin_amdgcn_exp2f(v)

#define ST_AGENT(p, v) __hip_atomic_store((p), (v), __ATOMIC_RELAXED, __HIP_MEMORY_SCOPE_AGENT)
#define LD_AGENT(p)    __hip_atomic_load((p), __ATOMIC_RELAXED, __HIP_MEMORY_SCOPE_AGENT)

__device__ __forceinline__ unsigned mbcnt64(unsigned long long m) {
    unsigned r = __builtin_amdgcn_mbcnt_lo((unsigned)m, 0u);
    return __builtin_amdgcn_mbcnt_hi((unsigned)(m >> 32), r);
}

// ws layout: float partial[18*256] @ 0 (18432 B); int ncls[32] @ 18432
// No memset node: every partial cell + ncls entry is overwritten every launch.
__global__ __launch_bounds__(256)
void hist_main(const float* __restrict__ x, const int* __restrict__ lab,
               float* __restrict__ partial, int* __restrict__ ncls) {
    const int cm1  = blockIdx.y;                  // 0..17
    const int c    = cm1 + 1;
    const int tid  = threadIdx.x;
    const int lane = tid & 63;
    const int wv   = tid >> 6;                    // 0..3
    const int f    = blockIdx.x * FPB + wv;       // this wave's feature

    __shared__ unsigned short idx_lds[4][1024];   // class-c pixel indices (u16), 8 KB
    __shared__ __align__(16) float val[4][VCAP + 8];
    __shared__ int n_sh[4];

    // ---- Phase 1: wave wv ballot-compacts its 1024-pixel quarter ----
    const int4* labv = (const int4*)lab;
    unsigned short* myidx = idx_lds[wv];
    unsigned cnt = 0;

#define SUBSCAN(L, S)                                                 \
    {                                                                 \
        bool in = ((L) == c);                                         \
        unsigned long long m = __ballot(in);                          \
        if (in) myidx[cnt + mbcnt64(m)] = (unsigned short)(pbase + (S)); \
        cnt += (unsigned)__popcll(m);                                 \
    }

    #pragma unroll
    for (int it = 0; it < 4; ++it) {
        int b4    = wv * 256 + it * 64 + lane;
        int4 lv   = labv[b4];
        int pbase = b4 * 4;
        SUBSCAN(lv.x, 0)
        SUBSCAN(lv.y, 1)
        SUBSCAN(lv.z, 2)
        SUBSCAN(lv.w, 3)
    }
#undef SUBSCAN

    if (lane == 0) n_sh[wv] = (int)cnt;
    __syncthreads();                              // the only barrier

    const int n = n_sh[0] + n_sh[1] + n_sh[2] + n_sh[3];   // block-uniform
    if (blockIdx.x == 0 && tid == 0) ST_AGENT(&ncls[c], n);

    if (n == 0) {                                 // still must overwrite our cell
        if (lane == 0) ST_AGENT(&partial[cm1 * NFEAT + f], 0.f);
        return;                                   // block-uniform: safe
    }

    // ---- Phase 2 (per wave): gather feature row + fused stats; stage chunk 0 ----
    const float* xrow  = x + (size_t)f * NPIX;
    float*       myval = val[wv];
    float s1 = 0.f, s2 = 0.f;
    {
        int pos = 0;
        #pragma unroll
        for (int s = 0; s < 4; ++s) {
            int ns_ = n_sh[s];
            const unsigned short* seg = idx_lds[s];
            for (int i = lane; i < ns_; i += 64) {
                float v = xrow[seg[i]];           // scattered, L1/L2-resident
                int j = pos + i;
                if (j < VCAP) myval[j] = v;
                s1 += v;
                s2 = fmaf(v, v, s2);
            }
            pos += ns_;
        }
    }
    #pragma unroll
    for (int off = 32; off; off >>= 1) {
        s1 += __shfl_xor(s1, off, 64);
        s2 += __shfl_xor(s2, off, 64);
    }
    const float fn  = (float)n;
    const float miu = s1 / fn;
    const float var = fmaxf(s2 / fn - miu * miu, 1e-12f);

    // ---- Phase 3 (per wave): KDE, lane = bin, poly-fma, 4 exp2 chains ----
    const float binv = -5.0f + 0.2f * (float)lane;
    const float cu   = (-12.5f / var) * LOG2E_F;  // -0.5/(var*0.04)*log2e
    const float bl   = -2.f * cu * binv;
    const float al   = cu * binv * binv;          // arg = (cu*v+bl)*v+al
    float a0 = 0.f, a1 = 0.f, a2 = 0.f, a3 = 0.f;

    for (int t0 = 0; t0 < n; t0 += VCAP) {
        if (t0 > 0) {                             // rare re-gather chunk (n > VCAP)
            int pos = 0;
            #pragma unroll
            for (int s = 0; s < 4; ++s) {
                int ns_ = n_sh[s];
                const unsigned short* seg = idx_lds[s];
                for (int i = lane; i < ns_; i += 64) {
                    int j = pos + i - t0;
                    if (j >= 0 && j < VCAP) myval[j] = xrow[seg[i]];
                }
                pos += ns_;
            }
        }
        int ns  = n - t0; if (ns > VCAP) ns = VCAP;
        int ns4 = (ns + 3) & ~3;
        if (lane < ns4 - ns) myval[ns + lane] = 1e19f;   // sentinel: exp2 -> 0
        #pragma unroll 4
        for (int i = 0; i < ns4; i += 4) {
            float4 v = *(const float4*)&myval[i];        // same-addr broadcast read
            a0 += EXP2F(fmaf(fmaf(cu, v.x, bl), v.x, al));
            a1 += EXP2F(fmaf(fmaf(cu, v.y, bl), v.y, al));
            a2 += EXP2F(fmaf(fmaf(cu, v.z, bl), v.z, al));
            a3 += EXP2F(fmaf(fmaf(cu, v.w, bl), v.w, al));
        }
    }

    // ---- Phase 4 (per wave): normalize + smooth-L1; direct per-wave store ----
    float kde = (a0 + a1) + (a2 + a3);
    float vs  = var * 0.04f;
    float dt  = binv - miu;
    float tg  = EXP2F(((-0.5f / var) * LOG2E_F) * (dt * dt));
    if (lane >= BINS) { kde = 0.f; tg = 0.f; }
    float sv = kde * rsqrtf(TWO_PI_F * vs);
    float tt = tg  * rsqrtf(TWO_PI_F * var);
    float ssum = sv, tsum = tt;
    #pragma unroll
    for (int off = 32; off; off >>= 1) {
        ssum += __shfl_xor(ssum, off, 64);
        tsum += __shfl_xor(tsum, off, 64);
    }
    float hist  = sv / fmaxf(ssum, 1e-12f);
    float tnorm = tt / tsum;
    float diff  = hist - tnorm;
    float ad    = fabsf(diff);
    float sl1   = (ad < 1.0f) ? 0.5f * diff * diff : (ad - 0.5f);
    if (lane >= BINS) sl1 = 0.f;
    #pragma unroll
    for (int off = 32; off; off >>= 1) sl1 += __shfl_xor(sl1, off, 64);
    if (lane == 0) ST_AGENT(&partial[cm1 * NFEAT + f], sl1);   // no 2nd barrier
}

// ---- finale: deterministic f64 reduction of 4608 cells (agent loads) ----
__global__ __launch_bounds__(512)
void hist_final(const float* __restrict__ partial, const int* __restrict__ ncls,
                float* __restrict__ out) {
    const int tid = threadIdx.x, lane = tid & 63, wave = tid >> 6;
    __shared__ double sd[8];

    double s = 0.0;
    for (int i = tid; i < NFEAT * (NCLS - 1); i += 512)
        s += (double)LD_AGENT(&partial[i]);
    #pragma unroll
    for (int off = 32; off; off >>= 1) s += __shfl_xor(s, off, 64);
    if (lane == 0) sd[wave] = s;
    __syncthreads();
    if (tid == 0) {
        double tot = 0.0;
        #pragma unroll
        for (int w = 0; w < 8; ++w) tot += sd[w];
        int active = 0;
        for (int cc = 1; cc < NCLS; ++cc) active += (LD_AGENT(&ncls[cc]) > 0) ? 1 : 0;
        double loss = tot / (double)(NFEAT * BINS) / ((double)active + 1e-12);
        out[0] = (float)loss;
    }
}

extern "C" void kernel_launch(void* const* d_in, const int* in_sizes, int n_in,
                              void* d_out, int out_size, void* d_ws, size_t ws_size,
                              hipStream_t stream) {
    const float* x   = (const float*)d_in[0];
    const int*   lab = (const int*)d_in[1];
    float* out       = (float*)d_out;
    float* partial   = (float*)d_ws;
    int*   ncls      = (int*)((char*)d_ws + 18432);

    hipLaunchKernelGGL(hist_main, dim3(NBX, NCLS - 1), dim3(256), 0, stream,
                       x, lab, partial, ncls);
    hipLaunchKernelGGL(hist_final, dim3(1), dim3(512), 0, stream,
                       partial, ncls, out);
}

// Round 18
// 22.998 us; speedup vs baseline: 1.0637x; 1.0164x over previous
//
#include <hip/hip_runtime.h>

#define NCLS 19
#define BINS 51
#define NPIX 4096
#define NFEAT 256
#define VCAP 256                   // staged values per wave (chunked beyond)
#define NPART ((NFEAT / 4) * (NCLS - 1))   // 1152 per-block partials
#define TWO_PI_F 6.2831853071795864769f
#define LOG2E_F 1.4426950408889634f
#define EXP2F(v) __builtin_amdgcn_exp2f(v)

#define ST_AGENT(p, v) __hip_atomic_store((p), (v), __ATOMIC_RELAXED, __HIP_MEMORY_SCOPE_AGENT)
#define LD_AGENT(p)    __hip_atomic_load((p), __ATOMIC_RELAXED, __HIP_MEMORY_SCOPE_AGENT)

__device__ __forceinline__ unsigned mbcnt64(unsigned long long m) {
    unsigned r = __builtin_amdgcn_mbcnt_lo((unsigned)m, 0u);
    return __builtin_amdgcn_mbcnt_hi((unsigned)(m >> 32), r);
}

// ws layout: float partial[1152] @ 0 (4608 B); int ncls[32] @ 4608
// No memset node: every partial cell + ncls entry is overwritten every launch.
__global__ __launch_bounds__(256)
void hist_main(const float* __restrict__ x, const int* __restrict__ lab,
               float* __restrict__ partial, int* __restrict__ ncls) {
    const int cm1  = blockIdx.y;                  // 0..17
    const int c    = cm1 + 1;
    const int tid  = threadIdx.x;
    const int lane = tid & 63;
    const int wv   = tid >> 6;                    // 0..3

    __shared__ unsigned short idx_lds[4][1024];   // class-c pixel indices (u16), 8 KB
    __shared__ __align__(16) float val[4][VCAP + 8];
    __shared__ int   n_sh[4];
    __shared__ float s_loss[4];

    // ---- Phase 1: cooperative scan — wave wv compacts its 1024-pixel quarter ----
    const int4* labv = (const int4*)lab;
    unsigned short* myidx = idx_lds[wv];
    unsigned cnt = 0;

#define SUBSCAN(L, S)                                                 \
    {                                                                 \
        bool in = ((L) == c);                                         \
        unsigned long long m = __ballot(in);                          \
        if (in) myidx[cnt + mbcnt64(m)] = (unsigned short)(pbase + (S)); \
        cnt += (unsigned)__popcll(m);                                 \
    }

    #pragma unroll
    for (int it = 0; it < 4; ++it) {
        int b4    = wv * 256 + it * 64 + lane;
        int4 lv   = labv[b4];
        int pbase = b4 * 4;
        SUBSCAN(lv.x, 0)
        SUBSCAN(lv.y, 1)
        SUBSCAN(lv.z, 2)
        SUBSCAN(lv.w, 3)
    }
#undef SUBSCAN

    if (lane == 0) n_sh[wv] = (int)cnt;
    __syncthreads();                              // barrier 1

    const int n = n_sh[0] + n_sh[1] + n_sh[2] + n_sh[3];   // block-uniform
    const int f = blockIdx.x * 4 + wv;            // this wave's feature
    if (blockIdx.x == 0 && tid == 0) ST_AGENT(&ncls[c], n);

    if (n == 0) {                                 // still must overwrite our cell
        if (tid == 0) ST_AGENT(&partial[cm1 * (NFEAT / 4) + blockIdx.x], 0.f);
        return;                                   // block-uniform: safe
    }

    // ---- Phase 2 (per wave): gather feature row + fused stats; stash chunk 0 ----
    const float* xrow  = x + (size_t)f * NPIX;
    float*       myval = val[wv];
    float s1 = 0.f, s2 = 0.f;
    {
        int pos = 0;
        #pragma unroll
        for (int s = 0; s < 4; ++s) {
            int ns_ = n_sh[s];
            const unsigned short* seg = idx_lds[s];
            for (int i = lane; i < ns_; i += 64) {
                float v = xrow[seg[i]];           // scattered, L2-resident
                int j = pos + i;
                if (j < VCAP) myval[j] = v;
                s1 += v;
                s2 = fmaf(v, v, s2);
            }
            pos += ns_;
        }
    }
    #pragma unroll
    for (int off = 32; off; off >>= 1) {
        s1 += __shfl_xor(s1, off, 64);
        s2 += __shfl_xor(s2, off, 64);
    }
    const float fn  = (float)n;
    const float miu = s1 / fn;
    const float var = fmaxf(s2 / fn - miu * miu, 1e-12f);

    // ---- Phase 3 (per wave): KDE, lane = bin, poly-fma, 4 exp2 chains ----
    const float binv = -5.0f + 0.2f * (float)lane;
    const float cu   = (-12.5f / var) * LOG2E_F;  // -0.5/(var*0.04)*log2e
    const float bl   = -2.f * cu * binv;
    const float al   = cu * binv * binv;          // arg = (cu*v+bl)*v+al
    float a0 = 0.f, a1 = 0.f, a2 = 0.f, a3 = 0.f;

    for (int t0 = 0; t0 < n; t0 += VCAP) {
        if (t0 > 0) {                             // rare re-gather chunk (n > VCAP)
            int pos = 0;
            #pragma unroll
            for (int s = 0; s < 4; ++s) {
                int ns_ = n_sh[s];
                const unsigned short* seg = idx_lds[s];
                for (int i = lane; i < ns_; i += 64) {
                    int j = pos + i - t0;
                    if (j >= 0 && j < VCAP) myval[j] = xrow[seg[i]];
                }
                pos += ns_;
            }
        }
        int ns  = n - t0; if (ns > VCAP) ns = VCAP;
        int ns4 = (ns + 3) & ~3;
        if (lane < ns4 - ns) myval[ns + lane] = 1e19f;   // sentinel: exp2 -> 0
        #pragma unroll 2
        for (int i = 0; i < ns4; i += 4) {
            float4 v = *(const float4*)&myval[i];        // same-addr broadcast read
            a0 += EXP2F(fmaf(fmaf(cu, v.x, bl), v.x, al));
            a1 += EXP2F(fmaf(fmaf(cu, v.y, bl), v.y, al));
            a2 += EXP2F(fmaf(fmaf(cu, v.z, bl), v.z, al));
            a3 += EXP2F(fmaf(fmaf(cu, v.w, bl), v.w, al));
        }
    }

    // ---- Phase 4 (per wave): normalize + smooth-L1 ----
    float kde = (a0 + a1) + (a2 + a3);
    float vs  = var * 0.04f;
    float dt  = binv - miu;
    float tg  = EXP2F(((-0.5f / var) * LOG2E_F) * (dt * dt));
    if (lane >= BINS) { kde = 0.f; tg = 0.f; }
    float sv = kde * rsqrtf(TWO_PI_F * vs);
    float tt = tg  * rsqrtf(TWO_PI_F * var);
    float ssum = sv, tsum = tt;
    #pragma unroll
    for (int off = 32; off; off >>= 1) {
        ssum += __shfl_xor(ssum, off, 64);
        tsum += __shfl_xor(tsum, off, 64);
    }
    float hist  = sv / fmaxf(ssum, 1e-12f);
    float tnorm = tt / tsum;
    float diff  = hist - tnorm;
    float ad    = fabsf(diff);
    float sl1   = (ad < 1.0f) ? 0.5f * diff * diff : (ad - 0.5f);
    if (lane >= BINS) sl1 = 0.f;
    #pragma unroll
    for (int off = 32; off; off >>= 1) sl1 += __shfl_xor(sl1, off, 64);
    if (lane == 0) s_loss[wv] = sl1;
    __syncthreads();                              // barrier 2 (block-uniform path)

    if (tid == 0) {
        float t = s_loss[0] + s_loss[1] + s_loss[2] + s_loss[3];
        ST_AGENT(&partial[cm1 * (NFEAT / 4) + blockIdx.x], t);
    }
}

// ---- finale: deterministic f64 reduction of 1152 cells (agent loads) ----
__global__ __launch_bounds__(256)
void hist_final(const float* __restrict__ partial, const int* __restrict__ ncls,
                float* __restrict__ out) {
    const int tid = threadIdx.x, lane = tid & 63, wave = tid >> 6;
    __shared__ double sd[4];

    double s = 0.0;
    for (int i = tid; i < NPART; i += 256)
        s += (double)LD_AGENT(&partial[i]);
    #pragma unroll
    for (int off = 32; off; off >>= 1) s += __shfl_xor(s, off, 64);
    if (lane == 0) sd[wave] = s;
    __syncthreads();
    if (tid == 0) {
        double tot = sd[0] + sd[1] + sd[2] + sd[3];
        int active = 0;
        for (int cc = 1; cc < NCLS; ++cc) active += (LD_AGENT(&ncls[cc]) > 0) ? 1 : 0;
        double loss = tot / (double)(NFEAT * BINS) / ((double)active + 1e-12);
        out[0] = (float)loss;
    }
}

extern "C" void kernel_launch(void* const* d_in, const int* in_sizes, int n_in,
                              void* d_out, int out_size, void* d_ws, size_t ws_size,
                              hipStream_t stream) {
    const float* x   = (const float*)d_in[0];
    const int*   lab = (const int*)d_in[1];
    float* out       = (float*)d_out;
    float* partial   = (float*)d_ws;
    int*   ncls      = (int*)((char*)d_ws + 4608);

    hipLaunchKernelGGL(hist_main, dim3(NFEAT / 4, NCLS - 1), dim3(256), 0, stream,
                       x, lab, partial, ncls);
    hipLaunchKernelGGL(hist_final, dim3(1), dim3(256), 0, stream,
                       partial, ncls, out);
}